// Round 6
// baseline (68.118 us; speedup 1.0000x reference)
//
#include <hip/hip_runtime.h>
#include <hip/hip_fp16.h>

#define OUT_H 7
#define OUT_W 7
#define NPOS  49
#define RATIO 2
#define SCALE 0.25f
#define CCH 256
#define FH 200
#define FW 200
#define FHW (FH * FW)          // 40000
#define LROW 68                // gather LDS row pad (floats)
#define TROW 72                // transpose LDS row pad (ushorts): 144 B, 16B-aligned

struct __align__(16) H8 { __half2 h[4]; };   // 8 fp16 channels

__device__ __forceinline__ void acc8(float (&a)[8], const H8& v, float w) {
    #pragma unroll
    for (int k = 0; k < 4; ++k) {
        a[2*k]   = fmaf(__low2float(v.h[k]),  w, a[2*k]);
        a[2*k+1] = fmaf(__high2float(v.h[k]), w, a[2*k+1]);
    }
}

__device__ __forceinline__ uint32_t part1by1(uint32_t x) {
    x &= 0xFFu;
    x = (x | (x << 4)) & 0x0F0Fu;
    x = (x | (x << 2)) & 0x3333u;
    x = (x | (x << 1)) & 0x5555u;
    return x;
}

// ---- Transpose (B,256,40000) fp32 -> (B,40000,256) fp16, + ROI morton sort -
// Block 0: bitonic-sorts ROI indices by (batch, morton(center)) into perm.
// Blocks 1..: 64ch x 64pix tiles; float4 reads (1KB/instr), dwordx4 stores.
__global__ __launch_bounds__(256) void transpose_sort(
    const float* __restrict__ in, __half* __restrict__ outT,
    const float* __restrict__ rois, uint32_t* __restrict__ perm,
    int N, int B)
{
    __shared__ __align__(16) char smem[64 * TROW * 2];   // 9216 B
    int bid = blockIdx.x;
    int tid = threadIdx.x;

    if (bid == 0) {
        // ---- ROI sort path (perf-only: any permutation is correct) ----
        uint64_t* keys = (uint64_t*)smem;
        if (N <= 1024) {
            for (int i = tid; i < 1024; i += 256) {
                uint64_t key = ~0ull;
                if (i < N) {
                    const float* r = rois + (size_t)i * 5;
                    int bb = (int)r[0];
                    float cx = 0.5f * (r[1] + r[3]) * SCALE;
                    float cy = 0.5f * (r[2] + r[4]) * SCALE;
                    uint32_t ix = (uint32_t)fminf(fmaxf(cx, 0.f), 255.f);
                    uint32_t iy = (uint32_t)fminf(fmaxf(cy, 0.f), 255.f);
                    uint32_t m = (part1by1(iy) << 1) | part1by1(ix) | ((uint32_t)bb << 16);
                    key = ((uint64_t)m << 32) | (uint32_t)i;
                }
                keys[i] = key;
            }
            __syncthreads();
            for (int sz = 2; sz <= 1024; sz <<= 1) {
                for (int j = sz >> 1; j > 0; j >>= 1) {
                    for (int i = tid; i < 1024; i += 256) {
                        int ixj = i ^ j;
                        if (ixj > i) {
                            uint64_t a = keys[i], c = keys[ixj];
                            bool asc = ((i & sz) == 0);
                            if ((a > c) == asc) { keys[i] = c; keys[ixj] = a; }
                        }
                    }
                    __syncthreads();
                }
            }
            for (int i = tid; i < N; i += 256) perm[i] = (uint32_t)keys[i];
        } else {
            for (int i = tid; i < N; i += 256) perm[i] = (uint32_t)i;
        }
        return;
    }

    // ---- transpose path ----
    bid -= 1;
    int pt   = bid % 625;               // 64-pixel tile
    int rest = bid / 625;
    int ct   = rest & 3;                // 64-channel tile
    int b    = rest >> 2;

    ushort* T = (ushort*)smem;          // T[px][c], row TROW ushorts
    int px0 = pt * 64, c0 = ct * 64;
    int c_l = tid >> 2;                 // 0..63
    int pxg = (tid & 3) << 4;           // 0,16,32,48

    const float* src = in + ((size_t)b * CCH + c0 + c_l) * FHW + px0 + pxg;
    #pragma unroll
    for (int k = 0; k < 4; ++k) {
        float4 v = *(const float4*)(src + 4 * k);
        T[(pxg + 4*k + 0) * TROW + c_l] = __half_as_ushort(__float2half(v.x));
        T[(pxg + 4*k + 1) * TROW + c_l] = __half_as_ushort(__float2half(v.y));
        T[(pxg + 4*k + 2) * TROW + c_l] = __half_as_ushort(__float2half(v.z));
        T[(pxg + 4*k + 3) * TROW + c_l] = __half_as_ushort(__float2half(v.w));
    }
    __syncthreads();

    char* dstB = (char*)(outT + ((size_t)b * FHW + px0) * CCH + c0);
    #pragma unroll
    for (int j2 = 0; j2 < 2; ++j2) {
        int unit = tid + 256 * j2;      // 0..511
        int pl = unit >> 3;             // pixel 0..63
        int o8 = unit & 7;              // 16 B chunk within 128 B pixel-slice
        uint4 val = *(const uint4*)&T[pl * TROW + o8 * 8];
        *(uint4*)(dstB + (size_t)pl * (CCH * 2) + o8 * 16) = val;
    }
}

// ---------------- ROI Align gather: 8 ch/lane, sorted + XCD-chunked ---------
__global__ __launch_bounds__(256) void roi_gather_v5(
    const __half* __restrict__ featT,  // (B, 40000, 256) fp16
    const float* __restrict__ rois,    // (N, 5)
    const uint32_t* __restrict__ perm, // (N)
    float* __restrict__ out,           // (N, 256, 7, 7)
    int N)
{
    int nblk = gridDim.x;
    int wg = (nblk % 8 == 0)
           ? ((blockIdx.x & 7) * (nblk >> 3) + (blockIdx.x >> 3))   // chunked XCD swizzle
           : blockIdx.x;
    int n  = (int)perm[wg >> 2];
    int cq = wg & 3;
    int tid = threadIdx.x;
    int wave = tid >> 6, lane = tid & 63;
    int g = lane >> 3;                  // position group 0..7
    int l = lane & 7;                   // channel group (8 ch)

    __shared__ float lds[NPOS * LROW];

    const float* r = rois + (size_t)n * 5;
    int   b  = (int)r[0];
    float x1 = r[1] * SCALE, y1 = r[2] * SCALE;
    float roi_w = fmaxf(r[3] * SCALE - x1, 1.0f);
    float roi_h = fmaxf(r[4] * SCALE - y1, 1.0f);
    float step_x = roi_w * (1.0f / (OUT_W * RATIO));
    float step_y = roi_h * (1.0f / (OUT_H * RATIO));

    const char* base = (const char*)featT + (size_t)b * ((size_t)FHW * CCH * 2);
    const uint32_t laneoff = (uint32_t)(cq * 64 + l * 8) * 2;

    #pragma unroll 1
    for (int rnd = 0; rnd < 2; ++rnd) {
        int p = rnd * 32 + wave * 8 + g;    // 0..63
        if (p < NPOS) {
            int ph = p / OUT_W;
            int pw = p - ph * OUT_W;
            float acc[8];
            #pragma unroll
            for (int k = 0; k < 8; ++k) acc[k] = 0.0f;

            #pragma unroll
            for (int iy = 0; iy < RATIO; ++iy) {
                float yy = y1 + ((float)(ph * RATIO + iy) + 0.5f) * step_y;
                bool  vy = (yy >= -1.0f) && (yy <= (float)FH);
                float yc = fminf(fmaxf(yy, 0.0f), (float)(FH - 1));
                int   yi0 = (int)yc;
                float ly = yc - (float)yi0, hy = 1.0f - ly;
                uint32_t row0  = (uint32_t)yi0 * (FW * CCH * 2);
                uint32_t rstep = (yi0 < FH - 1) ? (FW * CCH * 2) : 0u;

                #pragma unroll
                for (int ix = 0; ix < RATIO; ++ix) {
                    float xx = x1 + ((float)(pw * RATIO + ix) + 0.5f) * step_x;
                    bool  vx = (xx >= -1.0f) && (xx <= (float)FW);
                    float xc = fminf(fmaxf(xx, 0.0f), (float)(FW - 1));
                    int   xi0 = (int)xc;
                    float lx = xc - (float)xi0, hx = 1.0f - lx;
                    uint32_t dx = (xi0 < FW - 1) ? (CCH * 2) : 0u;

                    float vm  = (vy && vx) ? 0.25f : 0.0f;
                    float hyv = hy * vm, lyv = ly * vm;

                    uint32_t o00 = row0 + (uint32_t)xi0 * (CCH * 2) + laneoff;
                    H8 v00 = *(const H8*)(base + o00);
                    H8 v01 = *(const H8*)(base + o00 + dx);
                    H8 v10 = *(const H8*)(base + o00 + rstep);
                    H8 v11 = *(const H8*)(base + o00 + rstep + dx);

                    acc8(acc, v00, hyv * hx);
                    acc8(acc, v01, hyv * lx);
                    acc8(acc, v10, lyv * hx);
                    acc8(acc, v11, lyv * lx);
                }
            }
            float* lp = &lds[p * LROW + l * 8];
            *(float4*)lp       = make_float4(acc[0], acc[1], acc[2], acc[3]);
            *(float4*)(lp + 4) = make_float4(acc[4], acc[5], acc[6], acc[7]);
        }
    }
    __syncthreads();

    // Contiguous 64*49-float region of (N,C,7,7); write-once -> nontemporal.
    float* oblk = out + ((size_t)n * CCH + cq * 64) * NPOS;
    #pragma unroll 1
    for (int o = tid; o < 64 * NPOS; o += 256) {
        int c = o / NPOS;          // magic-mul
        int p = o - c * NPOS;
        __builtin_nontemporal_store(lds[p * LROW + c], &oblk[o]);
    }
}

// ---------------- Fallback: direct NCHW (round-1 kernel) --------------------
__global__ __launch_bounds__(256) void roi_align_kernel(
    const float* __restrict__ feat, const float* __restrict__ rois,
    float* __restrict__ out, int N, int C, int H, int W)
{
    int idx = blockIdx.x * blockDim.x + threadIdx.x;
    int total = N * C * OUT_H * OUT_W;
    if (idx >= total) return;
    int pw = idx % OUT_W;
    int ph = (idx / OUT_W) % OUT_H;
    int c  = (idx / (OUT_W * OUT_H)) % C;
    int n  = idx / (OUT_W * OUT_H * C);
    const float* r = rois + (size_t)n * 5;
    int   b  = (int)r[0];
    float x1 = r[1] * SCALE, y1 = r[2] * SCALE;
    float roi_w = fmaxf(r[3] * SCALE - x1, 1.0f);
    float roi_h = fmaxf(r[4] * SCALE - y1, 1.0f);
    float step_y = roi_h * (1.0f / (OUT_H * RATIO));
    float step_x = roi_w * (1.0f / (OUT_W * RATIO));
    const float* fptr = feat + ((size_t)b * C + c) * (size_t)(H * W);
    float acc = 0.0f;
    #pragma unroll
    for (int iy = 0; iy < RATIO; ++iy) {
        float y = y1 + ((float)(ph * RATIO + iy) + 0.5f) * step_y;
        bool vy = (y >= -1.0f) && (y <= (float)H);
        float ycl = fminf(fmaxf(y, 0.0f), (float)(H - 1));
        int y0 = (int)floorf(ycl), y1i = min(y0 + 1, H - 1);
        float ly = ycl - (float)y0, hy = 1.0f - ly;
        #pragma unroll
        for (int ix = 0; ix < RATIO; ++ix) {
            float x = x1 + ((float)(pw * RATIO + ix) + 0.5f) * step_x;
            bool vx = (x >= -1.0f) && (x <= (float)W);
            float xcl = fminf(fmaxf(x, 0.0f), (float)(W - 1));
            int x0 = (int)floorf(xcl), x1i = min(x0 + 1, W - 1);
            float lx = xcl - (float)x0, hx = 1.0f - lx;
            const float* row0 = fptr + (size_t)y0 * W;
            const float* row1 = fptr + (size_t)y1i * W;
            float v = hy * hx * row0[x0] + hy * lx * row0[x1i]
                    + ly * hx * row1[x0] + ly * lx * row1[x1i];
            acc += (vy && vx) ? v : 0.0f;
        }
    }
    out[idx] = acc * (1.0f / (RATIO * RATIO));
}

extern "C" void kernel_launch(void* const* d_in, const int* in_sizes, int n_in,
                              void* d_out, int out_size, void* d_ws, size_t ws_size,
                              hipStream_t stream) {
    const float* feat = (const float*)d_in[0];
    const float* rois = (const float*)d_in[1];
    float* out = (float*)d_out;

    const int N = in_sizes[1] / 5;
    const int B = in_sizes[0] / (CCH * FHW);

    size_t featTBytes = (size_t)B * FHW * CCH * sizeof(__half);
    size_t need = featTBytes + (size_t)N * sizeof(uint32_t);
    if (ws_size >= need) {
        __half* featT = (__half*)d_ws;
        uint32_t* perm = (uint32_t*)((char*)d_ws + featTBytes);
        transpose_sort<<<B * 4 * 625 + 1, 256, 0, stream>>>(
            feat, featT, rois, perm, N, B);
        roi_gather_v5<<<4 * N, 256, 0, stream>>>(featT, rois, perm, out, N);
    } else {
        int total = N * CCH * OUT_H * OUT_W;
        roi_align_kernel<<<(total + 255) / 256, 256, 0, stream>>>(
            feat, rois, out, N, CCH, FH, FW);
    }
}

// Round 8
// 64.496 us; speedup vs baseline: 1.0562x; 1.0562x over previous
//
#include <hip/hip_runtime.h>
#include <hip/hip_fp16.h>

#define OUT_H 7
#define OUT_W 7
#define NPOS  49
#define RATIO 2
#define SCALE 0.25f
#define CCH 256
#define FH 200
#define FW 200
#define FHW (FH * FW)          // 40000
#define LROW 68                // gather LDS row pad (floats)
#define TROW 72                // transpose LDS row pad (ushorts): 144 B

typedef float vfloat4 __attribute__((ext_vector_type(4)));   // builtin vec for nontemporal

struct __align__(16) H8 { __half2 h[4]; };   // 8 fp16 channels

__device__ __forceinline__ void acc8(float (&a)[8], const H8& v, float w) {
    #pragma unroll
    for (int k = 0; k < 4; ++k) {
        a[2*k]   = fmaf(__low2float(v.h[k]),  w, a[2*k]);
        a[2*k+1] = fmaf(__high2float(v.h[k]), w, a[2*k+1]);
    }
}

// ---- Transpose (B,256,40000) fp32 -> (B,40000,256) fp16, + ROI bucket sort -
// Block 0: 2-pass counting sort of ROI indices by (batch, 4x4 morton cell)
// into perm (~1-2 us, hidden under 2500 transpose blocks). Order within a
// bucket is irrelevant -> atomic scatter is fine.
// Blocks 1..: 64ch x 64px tiles; float4 nontemporal reads, dwordx4 stores.
__global__ __launch_bounds__(256) void transpose_sort(
    const float* __restrict__ in, __half* __restrict__ outT,
    const float* __restrict__ rois, uint32_t* __restrict__ perm,
    int N, int B)
{
    __shared__ __align__(16) char smem[64 * TROW * 2];   // 9216 B
    int bid = blockIdx.x;
    int tid = threadIdx.x;

    if (bid == 0) {
        // ---- counting-sort path (perf-only; any permutation is correct) ----
        unsigned char* key8 = (unsigned char*)smem;          // N <= 2048
        int* bcnt = (int*)(smem + 4096);                     // 64 buckets
        int* bpos = (int*)(smem + 4096 + 256);
        if (N <= 2048 && B <= 4) {
            for (int i = tid; i < 64; i += 256) bcnt[i] = 0;
            __syncthreads();
            for (int i = tid; i < N; i += 256) {
                const float* r = rois + (size_t)i * 5;
                int bb = min(max((int)r[0], 0), B - 1);
                float cx = 0.5f * (r[1] + r[3]) * SCALE;     // 0..FW
                float cy = 0.5f * (r[2] + r[4]) * SCALE;
                int gx = min(3, max(0, (int)(cx * (4.0f / FW))));
                int gy = min(3, max(0, (int)(cy * (4.0f / FH))));
                int m = ((gx & 1) | ((gy & 1) << 1) | ((gx >> 1) << 2) | ((gy >> 1) << 3));
                int k = (bb << 4) | m;
                key8[i] = (unsigned char)k;
                atomicAdd(&bcnt[k], 1);
            }
            __syncthreads();
            if (tid == 0) {
                int s = 0;
                for (int k = 0; k < 64; ++k) { bpos[k] = s; s += bcnt[k]; }
            }
            __syncthreads();
            for (int i = tid; i < N; i += 256) {
                int pos = atomicAdd(&bpos[key8[i]], 1);
                perm[pos] = (uint32_t)i;
            }
        } else {
            for (int i = tid; i < N; i += 256) perm[i] = (uint32_t)i;
        }
        return;
    }

    // ---- transpose path ----
    bid -= 1;
    int pt   = bid % 625;               // 64-pixel tile
    int rest = bid / 625;
    int ct   = rest & 3;                // 64-channel tile
    int b    = rest >> 2;

    ushort* T = (ushort*)smem;          // T[px][c], row TROW ushorts
    int px0 = pt * 64, c0 = ct * 64;
    int c_l = tid >> 2;                 // 0..63
    int pxg = (tid & 3) << 4;           // 0,16,32,48

    const float* src = in + ((size_t)b * CCH + c0 + c_l) * FHW + px0 + pxg;
    #pragma unroll
    for (int k = 0; k < 4; ++k) {
        vfloat4 v = __builtin_nontemporal_load((const vfloat4*)(src + 4 * k));
        T[(pxg + 4*k + 0) * TROW + c_l] = __half_as_ushort(__float2half(v.x));
        T[(pxg + 4*k + 1) * TROW + c_l] = __half_as_ushort(__float2half(v.y));
        T[(pxg + 4*k + 2) * TROW + c_l] = __half_as_ushort(__float2half(v.z));
        T[(pxg + 4*k + 3) * TROW + c_l] = __half_as_ushort(__float2half(v.w));
    }
    __syncthreads();

    char* dstB = (char*)(outT + ((size_t)b * FHW + px0) * CCH + c0);
    #pragma unroll
    for (int j2 = 0; j2 < 2; ++j2) {
        int unit = tid + 256 * j2;      // 0..511
        int pl = unit >> 3;             // pixel 0..63
        int o8 = unit & 7;              // 16 B chunk within 128 B pixel-slice
        uint4 val = *(const uint4*)&T[pl * TROW + o8 * 8];
        *(uint4*)(dstB + (size_t)pl * (CCH * 2) + o8 * 16) = val;
    }
}

// ---------------- ROI Align gather: 8 ch/lane, cq-major + XCD-chunked -------
// Logical wg -> (cq = wg/N, si = wg%N, n = perm[si]). With the chunked XCD
// swizzle each XCD serves ONE 128B channel-quarter over a morton-contiguous
// run of sorted ROIs -> small, reused L2 working set.
__global__ __launch_bounds__(256) void roi_gather_v6(
    const __half* __restrict__ featT,  // (B, 40000, 256) fp16
    const float* __restrict__ rois,    // (N, 5)
    const uint32_t* __restrict__ perm, // (N)
    float* __restrict__ out,           // (N, 256, 7, 7)
    int N)
{
    int nblk = gridDim.x;
    int wg = (nblk % 8 == 0)
           ? ((blockIdx.x & 7) * (nblk >> 3) + (blockIdx.x >> 3))
           : blockIdx.x;
    int cq = wg / N;                    // channel quarter (cq-major!)
    int si = wg - cq * N;
    int n  = (int)perm[si];
    int tid = threadIdx.x;
    int wave = tid >> 6, lane = tid & 63;
    int g = lane >> 3;                  // position group 0..7
    int l = lane & 7;                   // channel group (8 ch)

    __shared__ float lds[NPOS * LROW];

    const float* r = rois + (size_t)n * 5;
    int   b  = (int)r[0];
    float x1 = r[1] * SCALE, y1 = r[2] * SCALE;
    float roi_w = fmaxf(r[3] * SCALE - x1, 1.0f);
    float roi_h = fmaxf(r[4] * SCALE - y1, 1.0f);
    float step_x = roi_w * (1.0f / (OUT_W * RATIO));
    float step_y = roi_h * (1.0f / (OUT_H * RATIO));

    const char* base = (const char*)featT + (size_t)b * ((size_t)FHW * CCH * 2);
    const uint32_t laneoff = (uint32_t)(cq * 64 + l * 8) * 2;

    #pragma unroll 1
    for (int rnd = 0; rnd < 2; ++rnd) {
        int p = rnd * 32 + wave * 8 + g;    // 0..63
        if (p < NPOS) {
            int ph = p / OUT_W;
            int pw = p - ph * OUT_W;
            float acc[8];
            #pragma unroll
            for (int k = 0; k < 8; ++k) acc[k] = 0.0f;

            #pragma unroll
            for (int iy = 0; iy < RATIO; ++iy) {
                float yy = y1 + ((float)(ph * RATIO + iy) + 0.5f) * step_y;
                bool  vy = (yy >= -1.0f) && (yy <= (float)FH);
                float yc = fminf(fmaxf(yy, 0.0f), (float)(FH - 1));
                int   yi0 = (int)yc;
                float ly = yc - (float)yi0, hy = 1.0f - ly;
                uint32_t row0  = (uint32_t)yi0 * (FW * CCH * 2);
                uint32_t rstep = (yi0 < FH - 1) ? (FW * CCH * 2) : 0u;

                #pragma unroll
                for (int ix = 0; ix < RATIO; ++ix) {
                    float xx = x1 + ((float)(pw * RATIO + ix) + 0.5f) * step_x;
                    bool  vx = (xx >= -1.0f) && (xx <= (float)FW);
                    float xc = fminf(fmaxf(xx, 0.0f), (float)(FW - 1));
                    int   xi0 = (int)xc;
                    float lx = xc - (float)xi0, hx = 1.0f - lx;
                    uint32_t dx = (xi0 < FW - 1) ? (CCH * 2) : 0u;

                    float vm  = (vy && vx) ? 0.25f : 0.0f;
                    float hyv = hy * vm, lyv = ly * vm;

                    uint32_t o00 = row0 + (uint32_t)xi0 * (CCH * 2) + laneoff;
                    H8 v00 = *(const H8*)(base + o00);
                    H8 v01 = *(const H8*)(base + o00 + dx);
                    H8 v10 = *(const H8*)(base + o00 + rstep);
                    H8 v11 = *(const H8*)(base + o00 + rstep + dx);

                    acc8(acc, v00, hyv * hx);
                    acc8(acc, v01, hyv * lx);
                    acc8(acc, v10, lyv * hx);
                    acc8(acc, v11, lyv * lx);
                }
            }
            float* lp = &lds[p * LROW + l * 8];
            *(float4*)lp       = make_float4(acc[0], acc[1], acc[2], acc[3]);
            *(float4*)(lp + 4) = make_float4(acc[4], acc[5], acc[6], acc[7]);
        }
    }
    __syncthreads();

    // Contiguous 64*49-float region of (N,C,7,7); write-once -> nontemporal.
    float* oblk = out + ((size_t)n * CCH + cq * 64) * NPOS;
    #pragma unroll 1
    for (int o = tid; o < 64 * NPOS; o += 256) {
        int c = o / NPOS;          // magic-mul
        int p = o - c * NPOS;
        __builtin_nontemporal_store(lds[p * LROW + c], &oblk[o]);
    }
}

// ---------------- Fallback: direct NCHW (round-1 kernel) --------------------
__global__ __launch_bounds__(256) void roi_align_kernel(
    const float* __restrict__ feat, const float* __restrict__ rois,
    float* __restrict__ out, int N, int C, int H, int W)
{
    int idx = blockIdx.x * blockDim.x + threadIdx.x;
    int total = N * C * OUT_H * OUT_W;
    if (idx >= total) return;
    int pw = idx % OUT_W;
    int ph = (idx / OUT_W) % OUT_H;
    int c  = (idx / (OUT_W * OUT_H)) % C;
    int n  = idx / (OUT_W * OUT_H * C);
    const float* r = rois + (size_t)n * 5;
    int   b  = (int)r[0];
    float x1 = r[1] * SCALE, y1 = r[2] * SCALE;
    float roi_w = fmaxf(r[3] * SCALE - x1, 1.0f);
    float roi_h = fmaxf(r[4] * SCALE - y1, 1.0f);
    float step_y = roi_h * (1.0f / (OUT_H * RATIO));
    float step_x = roi_w * (1.0f / (OUT_W * RATIO));
    const float* fptr = feat + ((size_t)b * C + c) * (size_t)(H * W);
    float acc = 0.0f;
    #pragma unroll
    for (int iy = 0; iy < RATIO; ++iy) {
        float y = y1 + ((float)(ph * RATIO + iy) + 0.5f) * step_y;
        bool vy = (y >= -1.0f) && (y <= (float)H);
        float ycl = fminf(fmaxf(y, 0.0f), (float)(H - 1));
        int y0 = (int)floorf(ycl), y1i = min(y0 + 1, H - 1);
        float ly = ycl - (float)y0, hy = 1.0f - ly;
        #pragma unroll
        for (int ix = 0; ix < RATIO; ++ix) {
            float x = x1 + ((float)(pw * RATIO + ix) + 0.5f) * step_x;
            bool vx = (x >= -1.0f) && (x <= (float)W);
            float xcl = fminf(fmaxf(x, 0.0f), (float)(W - 1));
            int x0 = (int)floorf(xcl), x1i = min(x0 + 1, W - 1);
            float lx = xcl - (float)x0, hx = 1.0f - lx;
            const float* row0 = fptr + (size_t)y0 * W;
            const float* row1 = fptr + (size_t)y1i * W;
            float v = hy * hx * row0[x0] + hy * lx * row0[x1i]
                    + ly * hx * row1[x0] + ly * lx * row1[x1i];
            acc += (vy && vx) ? v : 0.0f;
        }
    }
    out[idx] = acc * (1.0f / (RATIO * RATIO));
}

extern "C" void kernel_launch(void* const* d_in, const int* in_sizes, int n_in,
                              void* d_out, int out_size, void* d_ws, size_t ws_size,
                              hipStream_t stream) {
    const float* feat = (const float*)d_in[0];
    const float* rois = (const float*)d_in[1];
    float* out = (float*)d_out;

    const int N = in_sizes[1] / 5;
    const int B = in_sizes[0] / (CCH * FHW);

    size_t featTBytes = (size_t)B * FHW * CCH * sizeof(__half);
    size_t need = featTBytes + (size_t)N * sizeof(uint32_t);
    if (ws_size >= need) {
        __half* featT = (__half*)d_ws;
        uint32_t* perm = (uint32_t*)((char*)d_ws + featTBytes);
        transpose_sort<<<B * 4 * 625 + 1, 256, 0, stream>>>(
            feat, featT, rois, perm, N, B);
        roi_gather_v6<<<4 * N, 256, 0, stream>>>(featT, rois, perm, out, N);
    } else {
        int total = N * CCH * OUT_H * OUT_W;
        roi_align_kernel<<<(total + 255) / 256, 256, 0, stream>>>(
            feat, rois, out, N, CCH, FH, FW);
    }
}

// Round 9
// 62.318 us; speedup vs baseline: 1.0931x; 1.0350x over previous
//
#include <hip/hip_runtime.h>
#include <hip/hip_fp16.h>

#define OUT_H 7
#define OUT_W 7
#define NPOS  49
#define RATIO 2
#define SCALE 0.25f
#define CCH 256
#define FH 200
#define FW 200
#define FHW (FH * FW)          // 40000
#define LROW 68                // gather LDS row pad (floats)

struct __align__(16) H8 { __half2 h[4]; };   // 8 fp16 channels

__device__ __forceinline__ void acc8(float (&a)[8], const H8& v, float w) {
    #pragma unroll
    for (int k = 0; k < 4; ++k) {
        a[2*k]   = fmaf(__low2float(v.h[k]),  w, a[2*k]);
        a[2*k+1] = fmaf(__high2float(v.h[k]), w, a[2*k+1]);
    }
}

// ---------------- Transpose: (B, 256, 40000) fp32 -> (B, 40000, 256) fp16 ---
// Round-5 proven version: HBM-bound at ~24 us (172 MB at ~7 TB/s). Scalar
// coalesced loads, ushort LDS tile (2-way max conflicts), uint stores.
__global__ __launch_bounds__(256) void transpose_cp(
    const float* __restrict__ in, __half* __restrict__ outT)
{
    int bid = blockIdx.x;               // grid = B * 4 * 625
    int pt   = bid % 625;               // pixel tile (64 pixels)
    int rest = bid / 625;
    int ct   = rest & 3;                // channel tile (64 ch)
    int b    = rest >> 2;

    __shared__ unsigned short tile[64][66];   // [pix][c]
    int tid = threadIdx.x;
    int pix0 = pt * 64, c0 = ct * 64;
    int xl = tid & 63;

    const float* src = in + ((size_t)b * CCH + c0) * FHW + pix0;
    #pragma unroll
    for (int k = 0; k < 16; ++k) {
        int cl = (tid >> 6) + 4 * k;    // 0..63
        tile[xl][cl] = __half_as_ushort(__float2half(src[(size_t)cl * FHW + xl]));
    }
    __syncthreads();

    __half* dst = outT + ((size_t)b * FHW + pix0) * CCH + c0;
    #pragma unroll
    for (int j = 0; j < 8; ++j) {
        int idx = tid + 256 * j;        // 0..2047
        int pl = idx >> 5;              // 0..63
        int cp = idx & 31;              // half2 index: c = 2*cp
        *(unsigned int*)((char*)dst + (size_t)pl * (CCH * 2) + 4 * cp) =
            *(const unsigned int*)&tile[pl][2 * cp];
    }
}

// ---------------- ROI Align gather: batched 16-load MLP ---------------------
// grid = 4N: block (n = bid>>2, cq = bid&3) owns 64 channels of ROI n.
// Lane = (g = position group, l = 8-channel group). Per position: compute all
// 4 sample coords/weights, then issue ALL 16 H8 loads into registers before
// any FMA (memory-level parallelism to cover L2/HBM latency), then 128 fmas.
// __launch_bounds__(256,4): VGPR cap 128, >=4 blocks/CU.
__global__ __launch_bounds__(256, 4) void roi_gather_v7(
    const __half* __restrict__ featT,  // (B, 40000, 256) fp16
    const float* __restrict__ rois,    // (N, 5)
    float* __restrict__ out,           // (N, 256, 7, 7)
    int N)
{
    int bid = blockIdx.x;
    int n  = bid >> 2;
    int cq = bid & 3;
    int tid = threadIdx.x;
    int wave = tid >> 6, lane = tid & 63;
    int g = lane >> 3;                  // position group 0..7
    int l = lane & 7;                   // channel group (8 ch)

    __shared__ float lds[NPOS * LROW];

    const float* r = rois + (size_t)n * 5;
    int   b  = (int)r[0];
    float x1 = r[1] * SCALE, y1 = r[2] * SCALE;
    float roi_w = fmaxf(r[3] * SCALE - x1, 1.0f);
    float roi_h = fmaxf(r[4] * SCALE - y1, 1.0f);
    float step_x = roi_w * (1.0f / (OUT_W * RATIO));
    float step_y = roi_h * (1.0f / (OUT_H * RATIO));

    const char* base = (const char*)featT + (size_t)b * ((size_t)FHW * CCH * 2);
    const uint32_t laneoff = (uint32_t)(cq * 64 + l * 8) * 2;

    #pragma unroll 1
    for (int rnd = 0; rnd < 2; ++rnd) {
        int p = rnd * 32 + wave * 8 + g;    // 0..63
        if (p < NPOS) {
            int ph = p / OUT_W;
            int pw = p - ph * OUT_W;

            uint32_t o00[4], dxx[4], rst[4];
            float w[4][4];
            #pragma unroll
            for (int iy = 0; iy < RATIO; ++iy) {
                float yy = y1 + ((float)(ph * RATIO + iy) + 0.5f) * step_y;
                bool  vy = (yy >= -1.0f) && (yy <= (float)FH);
                float yc = fminf(fmaxf(yy, 0.0f), (float)(FH - 1));
                int   yi0 = (int)yc;
                float ly = yc - (float)yi0, hy = 1.0f - ly;
                uint32_t row0  = (uint32_t)yi0 * (FW * CCH * 2);
                uint32_t rstep = (yi0 < FH - 1) ? (FW * CCH * 2) : 0u;
                #pragma unroll
                for (int ix = 0; ix < RATIO; ++ix) {
                    int s = iy * RATIO + ix;
                    float xx = x1 + ((float)(pw * RATIO + ix) + 0.5f) * step_x;
                    bool  vx = (xx >= -1.0f) && (xx <= (float)FW);
                    float xc = fminf(fmaxf(xx, 0.0f), (float)(FW - 1));
                    int   xi0 = (int)xc;
                    float lx = xc - (float)xi0, hx = 1.0f - lx;
                    float vm  = (vy && vx) ? 0.25f : 0.0f;
                    float hyv = hy * vm, lyv = ly * vm;
                    o00[s] = row0 + (uint32_t)xi0 * (CCH * 2) + laneoff;
                    dxx[s] = (xi0 < FW - 1) ? (CCH * 2) : 0u;
                    rst[s] = rstep;
                    w[s][0] = hyv * hx; w[s][1] = hyv * lx;
                    w[s][2] = lyv * hx; w[s][3] = lyv * lx;
                }
            }

            H8 v[16];
            #pragma unroll
            for (int s = 0; s < 4; ++s) {
                v[4*s+0] = *(const H8*)(base + o00[s]);
                v[4*s+1] = *(const H8*)(base + o00[s] + dxx[s]);
                v[4*s+2] = *(const H8*)(base + o00[s] + rst[s]);
                v[4*s+3] = *(const H8*)(base + o00[s] + rst[s] + dxx[s]);
            }

            float acc[8];
            #pragma unroll
            for (int k = 0; k < 8; ++k) acc[k] = 0.0f;
            #pragma unroll
            for (int s = 0; s < 4; ++s) {
                #pragma unroll
                for (int c4 = 0; c4 < 4; ++c4)
                    acc8(acc, v[4*s+c4], w[s][c4]);
            }

            float* lp = &lds[p * LROW + l * 8];
            *(float4*)lp       = make_float4(acc[0], acc[1], acc[2], acc[3]);
            *(float4*)(lp + 4) = make_float4(acc[4], acc[5], acc[6], acc[7]);
        }
    }
    __syncthreads();

    // Contiguous 64*49-float region of (N,C,7,7); write-once -> nontemporal.
    float* oblk = out + ((size_t)n * CCH + cq * 64) * NPOS;
    #pragma unroll 1
    for (int o = tid; o < 64 * NPOS; o += 256) {
        int c = o / NPOS;          // magic-mul
        int p = o - c * NPOS;
        __builtin_nontemporal_store(lds[p * LROW + c], &oblk[o]);
    }
}

// ---------------- Fallback: direct NCHW (round-1 kernel) --------------------
__global__ __launch_bounds__(256) void roi_align_kernel(
    const float* __restrict__ feat, const float* __restrict__ rois,
    float* __restrict__ out, int N, int C, int H, int W)
{
    int idx = blockIdx.x * blockDim.x + threadIdx.x;
    int total = N * C * OUT_H * OUT_W;
    if (idx >= total) return;
    int pw = idx % OUT_W;
    int ph = (idx / OUT_W) % OUT_H;
    int c  = (idx / (OUT_W * OUT_H)) % C;
    int n  = idx / (OUT_W * OUT_H * C);
    const float* r = rois + (size_t)n * 5;
    int   b  = (int)r[0];
    float x1 = r[1] * SCALE, y1 = r[2] * SCALE;
    float roi_w = fmaxf(r[3] * SCALE - x1, 1.0f);
    float roi_h = fmaxf(r[4] * SCALE - y1, 1.0f);
    float step_y = roi_h * (1.0f / (OUT_H * RATIO));
    float step_x = roi_w * (1.0f / (OUT_W * RATIO));
    const float* fptr = feat + ((size_t)b * C + c) * (size_t)(H * W);
    float acc = 0.0f;
    #pragma unroll
    for (int iy = 0; iy < RATIO; ++iy) {
        float y = y1 + ((float)(ph * RATIO + iy) + 0.5f) * step_y;
        bool vy = (y >= -1.0f) && (y <= (float)H);
        float ycl = fminf(fmaxf(y, 0.0f), (float)(H - 1));
        int y0 = (int)floorf(ycl), y1i = min(y0 + 1, H - 1);
        float ly = ycl - (float)y0, hy = 1.0f - ly;
        #pragma unroll
        for (int ix = 0; ix < RATIO; ++ix) {
            float x = x1 + ((float)(pw * RATIO + ix) + 0.5f) * step_x;
            bool vx = (x >= -1.0f) && (x <= (float)W);
            float xcl = fminf(fmaxf(x, 0.0f), (float)(W - 1));
            int x0 = (int)floorf(xcl), x1i = min(x0 + 1, W - 1);
            float lx = xcl - (float)x0, hx = 1.0f - lx;
            const float* row0 = fptr + (size_t)y0 * W;
            const float* row1 = fptr + (size_t)y1i * W;
            float v = hy * hx * row0[x0] + hy * lx * row0[x1i]
                    + ly * hx * row1[x0] + ly * lx * row1[x1i];
            acc += (vy && vx) ? v : 0.0f;
        }
    }
    out[idx] = acc * (1.0f / (RATIO * RATIO));
}

extern "C" void kernel_launch(void* const* d_in, const int* in_sizes, int n_in,
                              void* d_out, int out_size, void* d_ws, size_t ws_size,
                              hipStream_t stream) {
    const float* feat = (const float*)d_in[0];
    const float* rois = (const float*)d_in[1];
    float* out = (float*)d_out;

    const int N = in_sizes[1] / 5;
    const int B = in_sizes[0] / (CCH * FHW);

    size_t need = (size_t)B * FHW * CCH * sizeof(__half);
    if (ws_size >= need) {
        __half* featT = (__half*)d_ws;
        transpose_cp<<<B * 4 * 625, 256, 0, stream>>>(feat, featT);
        roi_gather_v7<<<4 * N, 256, 0, stream>>>(featT, rois, out, N);
    } else {
        int total = N * CCH * OUT_H * OUT_W;
        roi_align_kernel<<<(total + 255) / 256, 256, 0, stream>>>(
            feat, rois, out, N, CCH, FH, FW);
    }
}